// Round 7
// baseline (150.049 us; speedup 1.0000x reference)
//
#include <hip/hip_runtime.h>
#include <hip/hip_bf16.h>
#include <math.h>

// Problem constants (fixed by setup_inputs)
#define N_NODES   50000
#define N_EDGES   800000
#define N_REL     1000
#define DIM       128
#define DEPTH_L   2
#define OUT_STRIDE (DIM * (DEPTH_L + 1))   // 384

#define PERSIST_BLOCKS 2048                // 8 blocks/CU * 256 CU

typedef _Float16 h2 __attribute__((ext_vector_type(2)));

#if defined(__has_builtin)
#if __has_builtin(__builtin_amdgcn_fdot2)
#define FDOT2(a, b, c) __builtin_amdgcn_fdot2((a), (b), (c), false)
#endif
#endif
#ifndef FDOT2
#define FDOT2(a, b, c) ((c) + (float)(a).x * (float)(b).x + (float)(a).y * (float)(b).y)
#endif

// fast tanh: (e^{2x}-1)/(e^{2x}+1), clamped so exp never overflows.
__device__ __forceinline__ float fast_tanh(float x) {
    float cx = fminf(fmaxf(x, -15.f), 15.f);
    float e = __expf(2.f * cx);
    return (e - 1.f) * __frcp_rn(e + 1.f);
}

// ---------------------------------------------------------------------------
// Kernel 1: per-relation precompute (R+1 blocks; block N_REL writes the
// zero row used by edges with r_val==0).
// ---------------------------------------------------------------------------
__global__ __launch_bounds__(64) void prep_rel_kernel(
    const float* __restrict__ rel_emb,
    const float* __restrict__ attn_k,
    _Float16* __restrict__ rhat,
    float* __restrict__ att_rel)
{
    int r = blockIdx.x;
    int lane = threadIdx.x;
    if (r == N_REL) {                       // zero row / zero logit slot
        rhat[(size_t)r * DIM + lane]      = (_Float16)0.f;
        rhat[(size_t)r * DIM + lane + 64] = (_Float16)0.f;
        if (lane < DEPTH_L) att_rel[lane * (N_REL + 1) + N_REL] = 0.f;
        return;
    }
    float v0 = rel_emb[r * DIM + lane];
    float v1 = rel_emb[r * DIM + lane + 64];
    float ss = v0 * v0 + v1 * v1;
    #pragma unroll
    for (int o = 32; o >= 1; o >>= 1) ss += __shfl_xor(ss, o);
    float inv = 1.0f / fmaxf(sqrtf(ss), 1e-12f);
    float t0 = v0 * inv, t1 = v1 * inv;
    rhat[(size_t)r * DIM + lane]      = (_Float16)t0;
    rhat[(size_t)r * DIM + lane + 64] = (_Float16)t1;
    #pragma unroll
    for (int l = 0; l < DEPTH_L; ++l) {
        float d = t0 * attn_k[l * DIM + lane] + t1 * attn_k[l * DIM + lane + 64];
        #pragma unroll
        for (int o = 32; o >= 1; o >>= 1) d += __shfl_xor(d, o);
        if (lane == 0) att_rel[l * (N_REL + 1) + r] = d;
    }
}

// ---------------------------------------------------------------------------
// Kernel 2: CSR row pointers from the sorted src array (binary search).
// ---------------------------------------------------------------------------
__global__ __launch_bounds__(256) void rowptr_kernel(
    const int* __restrict__ src, int* __restrict__ rp)
{
    int n = blockIdx.x * blockDim.x + threadIdx.x;
    if (n > N_NODES) return;
    int lo = 0, hi = N_EDGES;
    while (lo < hi) {
        int mid = (lo + hi) >> 1;
        if (src[mid] < n) lo = mid + 1; else hi = mid;
    }
    rp[n] = lo;
}

// ---------------------------------------------------------------------------
// Kernel 3: FUSED tanh0 + softmax weights for both layers + edge records.
// Persistent: one wave per node per grid-stride iteration.
//   out[:,0:128] = tanh(features); fs0 = f16 mirror
//   einfo4[e] = { dst, rel' (N_REL if r_val==0), bits(w0), bits(w1) }
// ---------------------------------------------------------------------------
__global__ __launch_bounds__(256) void weights_tanh_kernel(
    const float* __restrict__ feat, float* __restrict__ out,
    _Float16* __restrict__ fs0,
    const int* __restrict__ dst, const int* __restrict__ relid,
    const float* __restrict__ rval, const int* __restrict__ rp,
    const float* __restrict__ att_rel,
    uint4* __restrict__ einfo4)
{
    int wid  = threadIdx.x >> 6;
    int lane = threadIdx.x & 63;
    int wave = blockIdx.x * 4 + wid;
    int nwaves = gridDim.x * 4;
    const float* ar0 = att_rel;
    const float* ar1 = att_rel + (N_REL + 1);

    for (int node = wave; node < N_NODES; node += nwaves) {
        // --- tanh of this node's feature row (lane: dims 2*lane, 2*lane+1) ---
        float2 v = *reinterpret_cast<const float2*>(feat + (size_t)node * DIM + 2 * lane);
        float y0 = fast_tanh(v.x), y1 = fast_tanh(v.y);
        *reinterpret_cast<float2*>(out + (size_t)node * OUT_STRIDE + 2 * lane)
            = make_float2(y0, y1);
        h2 pr; pr.x = (_Float16)y0; pr.y = (_Float16)y1;
        *reinterpret_cast<h2*>(fs0 + (size_t)node * DIM + 2 * lane) = pr;

        // --- softmax weights over this node's edges ---
        int start = rp[node], end = rp[node + 1];
        if (start >= end) continue;

        float m0 = -INFINITY, s0 = 0.f, m1 = -INFINITY, s1 = 0.f;
        for (int e = start + lane; e < end; e += 64) {
            int r = (rval[e] == 0.f) ? N_REL : relid[e];
            float l0 = ar0[r], l1 = ar1[r];
            if (l0 > m0) { s0 = s0 * __expf(m0 - l0) + 1.f; m0 = l0; }
            else         { s0 += __expf(l0 - m0); }
            if (l1 > m1) { s1 = s1 * __expf(m1 - l1) + 1.f; m1 = l1; }
            else         { s1 += __expf(l1 - m1); }
        }
        #pragma unroll
        for (int o = 32; o >= 1; o >>= 1) {
            float ma = __shfl_xor(m0, o), sa = __shfl_xor(s0, o);
            float mn = fmaxf(m0, ma);
            s0 = (mn == -INFINITY) ? 0.f : s0 * __expf(m0 - mn) + sa * __expf(ma - mn);
            m0 = mn;
            float mb = __shfl_xor(m1, o), sb = __shfl_xor(s1, o);
            float mo = fmaxf(m1, mb);
            s1 = (mo == -INFINITY) ? 0.f : s1 * __expf(m1 - mo) + sb * __expf(mb - mo);
            m1 = mo;
        }
        float i0 = 1.0f / s0, i1 = 1.0f / s1;
        for (int e = start + lane; e < end; e += 64) {
            int r = (rval[e] == 0.f) ? N_REL : relid[e];
            float w0 = __expf(ar0[r] - m0) * i0;
            float w1 = __expf(ar1[r] - m1) * i1;
            einfo4[e] = make_uint4((unsigned)dst[e], (unsigned)r,
                                   __float_as_uint(w0), __float_as_uint(w1));
        }
    }
}

// ---------------------------------------------------------------------------
// Kernel 4 (per layer L): FUSED gather + reflect + accumulate, f16 inputs.
// Persistent grid-stride: one wave per node per iteration; chunks of 8 edges;
// 8 lanes/edge; lane owns 16 dims. 3-step halving butterfly leaves lane (g,q)
// holding dims 16q+2g, 16q+2g+1.
// ---------------------------------------------------------------------------
template<int L>
__global__ __launch_bounds__(256) void layer_fused_kernel(
    const _Float16* __restrict__ fs_in,   // [N,128] f16
    float* __restrict__ fout,             // column block in d_out
    _Float16* __restrict__ fs_out,        // [N,128] f16 mirror (L==0 only)
    const uint4* __restrict__ einfo4,
    const int* __restrict__ rp,
    const _Float16* __restrict__ rhat)    // [(R+1),128] f16
{
    int wid  = threadIdx.x >> 6;
    int lane = threadIdx.x & 63;
    int wave = blockIdx.x * 4 + wid;
    int nwaves = gridDim.x * 4;
    int g = lane >> 3;      // edge slot within chunk (0..7)
    int q = lane & 7;       // dim group: dims [16q, 16q+16)

    const char* fbase = (const char*)fs_in + 32 * q;   // +16 dims * 2B per q
    const char* tbase = (const char*)rhat  + 32 * q;
    int g0 = (lane >> 3) & 1, g1 = (lane >> 4) & 1, g2 = (lane >> 5) & 1;

    for (int node = wave; node < N_NODES; node += nwaves) {
        int start = rp[node], end = rp[node + 1];

        float a[16];
        #pragma unroll
        for (int i = 0; i < 16; ++i) a[i] = 0.f;

        for (int e0 = start; e0 < end; e0 += 8) {
            int e = e0 + g;
            bool valid = (e < end);
            int ec = valid ? e : (end - 1);
            uint4 ei = einfo4[ec];
            float w = valid ? __uint_as_float((L == 0) ? ei.z : ei.w) : 0.f;

            const uint4* hp = reinterpret_cast<const uint4*>(fbase + (size_t)ei.x * 256);
            const uint4* tp = reinterpret_cast<const uint4*>(tbase + (size_t)ei.y * 256);
            uint4 hu0 = hp[0], hu1 = hp[1];
            uint4 tu0 = tp[0], tu1 = tp[1];

            h2 hh[8], tt[8];
            hh[0] = __builtin_bit_cast(h2, hu0.x); hh[1] = __builtin_bit_cast(h2, hu0.y);
            hh[2] = __builtin_bit_cast(h2, hu0.z); hh[3] = __builtin_bit_cast(h2, hu0.w);
            hh[4] = __builtin_bit_cast(h2, hu1.x); hh[5] = __builtin_bit_cast(h2, hu1.y);
            hh[6] = __builtin_bit_cast(h2, hu1.z); hh[7] = __builtin_bit_cast(h2, hu1.w);
            tt[0] = __builtin_bit_cast(h2, tu0.x); tt[1] = __builtin_bit_cast(h2, tu0.y);
            tt[2] = __builtin_bit_cast(h2, tu0.z); tt[3] = __builtin_bit_cast(h2, tu0.w);
            tt[4] = __builtin_bit_cast(h2, tu1.x); tt[5] = __builtin_bit_cast(h2, tu1.y);
            tt[6] = __builtin_bit_cast(h2, tu1.z); tt[7] = __builtin_bit_cast(h2, tu1.w);

            float d0 = 0.f, d1 = 0.f;
            #pragma unroll
            for (int p = 0; p < 8; p += 2) {
                d0 = FDOT2(hh[p],     tt[p],     d0);
                d1 = FDOT2(hh[p + 1], tt[p + 1], d1);
            }
            float d = d0 + d1;
            d += __shfl_xor(d, 1);
            d += __shfl_xor(d, 2);
            d += __shfl_xor(d, 4);
            float cf = -2.f * w * d;

            #pragma unroll
            for (int p = 0; p < 8; ++p) {
                a[2*p]   = fmaf(w,  (float)hh[p].x, a[2*p]);
                a[2*p]   = fmaf(cf, (float)tt[p].x, a[2*p]);
                a[2*p+1] = fmaf(w,  (float)hh[p].y, a[2*p+1]);
                a[2*p+1] = fmaf(cf, (float)tt[p].y, a[2*p+1]);
            }
        }

        // Halving butterfly over the 8 edge-groups. After 3 steps, lane (g,q)
        // holds the full sums for dims 16q+2g, 16q+2g+1.
        float b1[8];
        #pragma unroll
        for (int j = 0; j < 8; ++j) {
            int J0 = ((j >> 2) & 1) * 8 + ((j >> 1) & 1) * 4 + (j & 1);
            float keep = g0 ? a[J0 + 2] : a[J0];
            float send = g0 ? a[J0] : a[J0 + 2];
            b1[j] = keep + __shfl_xor(send, 8);
        }
        float b2[4];
        #pragma unroll
        for (int k = 0; k < 4; ++k) {
            int K0 = ((k >> 1) & 1) * 4 + (k & 1);
            float keep = g1 ? b1[K0 + 2] : b1[K0];
            float send = g1 ? b1[K0] : b1[K0 + 2];
            b2[k] = keep + __shfl_xor(send, 16);
        }
        float c0, c1;
        {
            float keep = g2 ? b2[2] : b2[0];
            float send = g2 ? b2[0] : b2[2];
            c0 = keep + __shfl_xor(send, 32);
        }
        {
            float keep = g2 ? b2[3] : b2[1];
            float send = g2 ? b2[1] : b2[3];
            c1 = keep + __shfl_xor(send, 32);
        }

        float y0 = fast_tanh(c0), y1 = fast_tanh(c1);
        int dimo = 16 * q + 2 * g;
        *reinterpret_cast<float2*>(fout + (size_t)node * OUT_STRIDE + dimo)
            = make_float2(y0, y1);
        if (L == 0) {
            h2 pr; pr.x = (_Float16)y0; pr.y = (_Float16)y1;
            *reinterpret_cast<h2*>(fs_out + (size_t)node * DIM + dimo) = pr;
        }
    }
}

// ---------------------------------------------------------------------------
extern "C" void kernel_launch(void* const* d_in, const int* in_sizes, int n_in,
                              void* d_out, int out_size, void* d_ws, size_t ws_size,
                              hipStream_t stream)
{
    const float* features = (const float*)d_in[0];
    const float* rel_emb  = (const float*)d_in[1];
    const int*   adj      = (const int*)d_in[2];   // [2, E]: src | dst
    const int*   r_index  = (const int*)d_in[3];   // [2, E]: arange | rel
    const float* r_val    = (const float*)d_in[4];
    const float* attn_k   = (const float*)d_in[8]; // [DEPTH, D]
    float* out = (float*)d_out;

    const int* src   = adj;
    const int* dst   = adj + N_EDGES;
    const int* relid = r_index + N_EDGES;

    // Workspace carve-up (~39 MB)
    char* base = (char*)d_ws;
    _Float16* rhat    = (_Float16*)base;                // (R+1)*128*2 = 256256 B
    float*    att_rel = (float*)(base + 256256);        // 2*(R+1)*4   =   8008 B
    int*      rp      = (int*)(base + 264264);          // 50001*4     = 200004 B
    uint4*    einfo4  = (uint4*)(base + 464272);        // 800000*16   = 12.8 MB
    _Float16* fs0     = (_Float16*)(base + 464272 + (size_t)N_EDGES * 16); // 12.8 MB
    _Float16* fs1     = fs0 + (size_t)N_NODES * DIM;                       // 12.8 MB

    prep_rel_kernel<<<N_REL + 1, 64, 0, stream>>>(rel_emb, attn_k, rhat, att_rel);
    rowptr_kernel<<<(N_NODES + 1 + 255) / 256, 256, 0, stream>>>(src, rp);
    weights_tanh_kernel<<<PERSIST_BLOCKS, 256, 0, stream>>>(
        features, out, fs0, dst, relid, r_val, rp, att_rel, einfo4);

    layer_fused_kernel<0><<<PERSIST_BLOCKS, 256, 0, stream>>>(
        fs0, out + 1 * DIM, fs1, einfo4, rp, rhat);
    layer_fused_kernel<1><<<PERSIST_BLOCKS, 256, 0, stream>>>(
        fs1, out + 2 * DIM, fs0, einfo4, rp, rhat);
}

// Round 8
// 134.498 us; speedup vs baseline: 1.1156x; 1.1156x over previous
//
#include <hip/hip_runtime.h>
#include <hip/hip_bf16.h>
#include <math.h>

// Problem constants (fixed by setup_inputs)
#define N_NODES   50000
#define N_EDGES   800000
#define N_REL     1000
#define DIM       128
#define DEPTH_L   2
#define OUT_STRIDE (DIM * (DEPTH_L + 1))   // 384

typedef _Float16 h2 __attribute__((ext_vector_type(2)));

#if defined(__has_builtin)
#if __has_builtin(__builtin_amdgcn_fdot2)
#define FDOT2(a, b, c) __builtin_amdgcn_fdot2((a), (b), (c), false)
#endif
#endif
#ifndef FDOT2
#define FDOT2(a, b, c) ((c) + (float)(a).x * (float)(b).x + (float)(a).y * (float)(b).y)
#endif

// fast tanh: (e^{2x}-1)/(e^{2x}+1), clamped so exp never overflows.
__device__ __forceinline__ float fast_tanh(float x) {
    float cx = fminf(fmaxf(x, -15.f), 15.f);
    float e = __expf(2.f * cx);
    return (e - 1.f) * __frcp_rn(e + 1.f);
}

// ---------------------------------------------------------------------------
// Kernel 1: per-relation precompute (R+1 blocks; block N_REL writes the
// zero row used by edges with r_val==0).
// ---------------------------------------------------------------------------
__global__ __launch_bounds__(64) void prep_rel_kernel(
    const float* __restrict__ rel_emb,
    const float* __restrict__ attn_k,
    _Float16* __restrict__ rhat,
    float* __restrict__ att_rel)
{
    int r = blockIdx.x;
    int lane = threadIdx.x;
    if (r == N_REL) {                       // zero row / zero logit slot
        rhat[(size_t)r * DIM + lane]      = (_Float16)0.f;
        rhat[(size_t)r * DIM + lane + 64] = (_Float16)0.f;
        if (lane < DEPTH_L) att_rel[lane * (N_REL + 1) + N_REL] = 0.f;
        return;
    }
    float v0 = rel_emb[r * DIM + lane];
    float v1 = rel_emb[r * DIM + lane + 64];
    float ss = v0 * v0 + v1 * v1;
    #pragma unroll
    for (int o = 32; o >= 1; o >>= 1) ss += __shfl_xor(ss, o);
    float inv = 1.0f / fmaxf(sqrtf(ss), 1e-12f);
    float t0 = v0 * inv, t1 = v1 * inv;
    rhat[(size_t)r * DIM + lane]      = (_Float16)t0;
    rhat[(size_t)r * DIM + lane + 64] = (_Float16)t1;
    #pragma unroll
    for (int l = 0; l < DEPTH_L; ++l) {
        float d = t0 * attn_k[l * DIM + lane] + t1 * attn_k[l * DIM + lane + 64];
        #pragma unroll
        for (int o = 32; o >= 1; o >>= 1) d += __shfl_xor(d, o);
        if (lane == 0) att_rel[l * (N_REL + 1) + r] = d;
    }
}

// ---------------------------------------------------------------------------
// Kernel 2: CSR row pointers from the sorted src array (binary search).
// ---------------------------------------------------------------------------
__global__ __launch_bounds__(256) void rowptr_kernel(
    const int* __restrict__ src, int* __restrict__ rp)
{
    int n = blockIdx.x * blockDim.x + threadIdx.x;
    if (n > N_NODES) return;
    int lo = 0, hi = N_EDGES;
    while (lo < hi) {
        int mid = (lo + hi) >> 1;
        if (src[mid] < n) lo = mid + 1; else hi = mid;
    }
    rp[n] = lo;
}

// ---------------------------------------------------------------------------
// Kernel 3: FUSED tanh0 + softmax weights for both layers + edge records.
// One wave per node.
// ---------------------------------------------------------------------------
__global__ __launch_bounds__(256) void weights_tanh_kernel(
    const float* __restrict__ feat, float* __restrict__ out,
    _Float16* __restrict__ fs0,
    const int* __restrict__ dst, const int* __restrict__ relid,
    const float* __restrict__ rval, const int* __restrict__ rp,
    const float* __restrict__ att_rel,
    uint4* __restrict__ einfo4)
{
    int wid  = threadIdx.x >> 6;
    int lane = threadIdx.x & 63;
    int node = blockIdx.x * 4 + wid;
    if (node >= N_NODES) return;

    // --- tanh of this node's feature row (lane: dims 2*lane, 2*lane+1) ---
    float2 v = *reinterpret_cast<const float2*>(feat + (size_t)node * DIM + 2 * lane);
    float y0 = fast_tanh(v.x), y1 = fast_tanh(v.y);
    *reinterpret_cast<float2*>(out + (size_t)node * OUT_STRIDE + 2 * lane)
        = make_float2(y0, y1);
    h2 pr; pr.x = (_Float16)y0; pr.y = (_Float16)y1;
    *reinterpret_cast<h2*>(fs0 + (size_t)node * DIM + 2 * lane) = pr;

    // --- softmax weights over this node's edges ---
    int start = rp[node], end = rp[node + 1];
    if (start >= end) return;
    const float* ar0 = att_rel;
    const float* ar1 = att_rel + (N_REL + 1);

    float m0 = -INFINITY, s0 = 0.f, m1 = -INFINITY, s1 = 0.f;
    for (int e = start + lane; e < end; e += 64) {
        int r = (rval[e] == 0.f) ? N_REL : relid[e];
        float l0 = ar0[r], l1 = ar1[r];
        if (l0 > m0) { s0 = s0 * __expf(m0 - l0) + 1.f; m0 = l0; }
        else         { s0 += __expf(l0 - m0); }
        if (l1 > m1) { s1 = s1 * __expf(m1 - l1) + 1.f; m1 = l1; }
        else         { s1 += __expf(l1 - m1); }
    }
    #pragma unroll
    for (int o = 32; o >= 1; o >>= 1) {
        float ma = __shfl_xor(m0, o), sa = __shfl_xor(s0, o);
        float mn = fmaxf(m0, ma);
        s0 = (mn == -INFINITY) ? 0.f : s0 * __expf(m0 - mn) + sa * __expf(ma - mn);
        m0 = mn;
        float mb = __shfl_xor(m1, o), sb = __shfl_xor(s1, o);
        float mo = fmaxf(m1, mb);
        s1 = (mo == -INFINITY) ? 0.f : s1 * __expf(m1 - mo) + sb * __expf(mb - mo);
        m1 = mo;
    }
    float i0 = 1.0f / s0, i1 = 1.0f / s1;
    for (int e = start + lane; e < end; e += 64) {
        int r = (rval[e] == 0.f) ? N_REL : relid[e];
        float w0 = __expf(ar0[r] - m0) * i0;
        float w1 = __expf(ar1[r] - m1) * i1;
        einfo4[e] = make_uint4((unsigned)dst[e], (unsigned)r,
                               __float_as_uint(w0), __float_as_uint(w1));
    }
}

// ---------------------------------------------------------------------------
// Kernel 4 (per layer L): FUSED gather + reflect + accumulate, f16 inputs.
// One wave per node; 16-edge iterations = TWO software-pipelined 8-edge
// sub-chunks (all loads of both sub-chunks issue before either compute).
// 8 lanes/edge; lane owns 16 dims; 3-step halving butterfly epilogue.
// ---------------------------------------------------------------------------
template<int L>
__global__ __launch_bounds__(256) void layer_fused_kernel(
    const _Float16* __restrict__ fs_in,   // [N,128] f16
    float* __restrict__ fout,             // column block in d_out
    _Float16* __restrict__ fs_out,        // [N,128] f16 mirror (L==0 only)
    const uint4* __restrict__ einfo4,
    const int* __restrict__ rp,
    const _Float16* __restrict__ rhat)    // [(R+1),128] f16
{
    int wid  = threadIdx.x >> 6;
    int lane = threadIdx.x & 63;
    int node = blockIdx.x * 4 + wid;
    if (node >= N_NODES) return;
    int start = rp[node], end = rp[node + 1];
    int g = lane >> 3;      // edge slot within sub-chunk (0..7)
    int q = lane & 7;       // dim group: dims [16q, 16q+16)

    const char* fbase = (const char*)fs_in + 32 * q;   // +16 dims * 2B per q
    const char* tbase = (const char*)rhat  + 32 * q;
    int g0 = (lane >> 3) & 1, g1 = (lane >> 4) & 1, g2 = (lane >> 5) & 1;

    float a[16];
    #pragma unroll
    for (int i = 0; i < 16; ++i) a[i] = 0.f;

    for (int e0 = start; e0 < end; e0 += 16) {
        // ---------- load phase: sub-chunk A ----------
        int eA = e0 + g;
        bool vA = (eA < end);
        int ecA = vA ? eA : (end - 1);
        uint4 eiA = einfo4[ecA];
        const uint4* hpA = reinterpret_cast<const uint4*>(fbase + (size_t)eiA.x * 256);
        const uint4* tpA = reinterpret_cast<const uint4*>(tbase + (size_t)eiA.y * 256);
        uint4 huA0 = hpA[0], huA1 = hpA[1];
        uint4 tuA0 = tpA[0], tuA1 = tpA[1];
        float wA = vA ? __uint_as_float((L == 0) ? eiA.z : eiA.w) : 0.f;

        // ---------- load phase: sub-chunk B (if present) ----------
        bool haveB = (e0 + 8 < end);
        uint4 huB0, huB1, tuB0, tuB1;
        float wB = 0.f;
        if (haveB) {
            int eB = e0 + 8 + g;
            bool vB = (eB < end);
            int ecB = vB ? eB : (end - 1);
            uint4 eiB = einfo4[ecB];
            const uint4* hpB = reinterpret_cast<const uint4*>(fbase + (size_t)eiB.x * 256);
            const uint4* tpB = reinterpret_cast<const uint4*>(tbase + (size_t)eiB.y * 256);
            huB0 = hpB[0]; huB1 = hpB[1];
            tuB0 = tpB[0]; tuB1 = tpB[1];
            wB = vB ? __uint_as_float((L == 0) ? eiB.z : eiB.w) : 0.f;
        }

        // ---------- compute A ----------
        {
            h2 hh[8], tt[8];
            hh[0] = __builtin_bit_cast(h2, huA0.x); hh[1] = __builtin_bit_cast(h2, huA0.y);
            hh[2] = __builtin_bit_cast(h2, huA0.z); hh[3] = __builtin_bit_cast(h2, huA0.w);
            hh[4] = __builtin_bit_cast(h2, huA1.x); hh[5] = __builtin_bit_cast(h2, huA1.y);
            hh[6] = __builtin_bit_cast(h2, huA1.z); hh[7] = __builtin_bit_cast(h2, huA1.w);
            tt[0] = __builtin_bit_cast(h2, tuA0.x); tt[1] = __builtin_bit_cast(h2, tuA0.y);
            tt[2] = __builtin_bit_cast(h2, tuA0.z); tt[3] = __builtin_bit_cast(h2, tuA0.w);
            tt[4] = __builtin_bit_cast(h2, tuA1.x); tt[5] = __builtin_bit_cast(h2, tuA1.y);
            tt[6] = __builtin_bit_cast(h2, tuA1.z); tt[7] = __builtin_bit_cast(h2, tuA1.w);
            float d0 = 0.f, d1 = 0.f;
            #pragma unroll
            for (int p = 0; p < 8; p += 2) {
                d0 = FDOT2(hh[p],     tt[p],     d0);
                d1 = FDOT2(hh[p + 1], tt[p + 1], d1);
            }
            float d = d0 + d1;
            d += __shfl_xor(d, 1);
            d += __shfl_xor(d, 2);
            d += __shfl_xor(d, 4);
            float cf = -2.f * wA * d;
            #pragma unroll
            for (int p = 0; p < 8; ++p) {
                a[2*p]   = fmaf(wA, (float)hh[p].x, a[2*p]);
                a[2*p]   = fmaf(cf, (float)tt[p].x, a[2*p]);
                a[2*p+1] = fmaf(wA, (float)hh[p].y, a[2*p+1]);
                a[2*p+1] = fmaf(cf, (float)tt[p].y, a[2*p+1]);
            }
        }

        // ---------- compute B ----------
        if (haveB) {
            h2 hh[8], tt[8];
            hh[0] = __builtin_bit_cast(h2, huB0.x); hh[1] = __builtin_bit_cast(h2, huB0.y);
            hh[2] = __builtin_bit_cast(h2, huB0.z); hh[3] = __builtin_bit_cast(h2, huB0.w);
            hh[4] = __builtin_bit_cast(h2, huB1.x); hh[5] = __builtin_bit_cast(h2, huB1.y);
            hh[6] = __builtin_bit_cast(h2, huB1.z); hh[7] = __builtin_bit_cast(h2, huB1.w);
            tt[0] = __builtin_bit_cast(h2, tuB0.x); tt[1] = __builtin_bit_cast(h2, tuB0.y);
            tt[2] = __builtin_bit_cast(h2, tuB0.z); tt[3] = __builtin_bit_cast(h2, tuB0.w);
            tt[4] = __builtin_bit_cast(h2, tuB1.x); tt[5] = __builtin_bit_cast(h2, tuB1.y);
            tt[6] = __builtin_bit_cast(h2, tuB1.z); tt[7] = __builtin_bit_cast(h2, tuB1.w);
            float d0 = 0.f, d1 = 0.f;
            #pragma unroll
            for (int p = 0; p < 8; p += 2) {
                d0 = FDOT2(hh[p],     tt[p],     d0);
                d1 = FDOT2(hh[p + 1], tt[p + 1], d1);
            }
            float d = d0 + d1;
            d += __shfl_xor(d, 1);
            d += __shfl_xor(d, 2);
            d += __shfl_xor(d, 4);
            float cf = -2.f * wB * d;
            #pragma unroll
            for (int p = 0; p < 8; ++p) {
                a[2*p]   = fmaf(wB, (float)hh[p].x, a[2*p]);
                a[2*p]   = fmaf(cf, (float)tt[p].x, a[2*p]);
                a[2*p+1] = fmaf(wB, (float)hh[p].y, a[2*p+1]);
                a[2*p+1] = fmaf(cf, (float)tt[p].y, a[2*p+1]);
            }
        }
    }

    // Halving butterfly over the 8 edge-groups. After 3 steps, lane (g,q)
    // holds the full sums for dims 16q+2g, 16q+2g+1.
    float b1[8];
    #pragma unroll
    for (int j = 0; j < 8; ++j) {
        int J0 = ((j >> 2) & 1) * 8 + ((j >> 1) & 1) * 4 + (j & 1);
        float keep = g0 ? a[J0 + 2] : a[J0];
        float send = g0 ? a[J0] : a[J0 + 2];
        b1[j] = keep + __shfl_xor(send, 8);
    }
    float b2[4];
    #pragma unroll
    for (int k = 0; k < 4; ++k) {
        int K0 = ((k >> 1) & 1) * 4 + (k & 1);
        float keep = g1 ? b1[K0 + 2] : b1[K0];
        float send = g1 ? b1[K0] : b1[K0 + 2];
        b2[k] = keep + __shfl_xor(send, 16);
    }
    float c0, c1;
    {
        float keep = g2 ? b2[2] : b2[0];
        float send = g2 ? b2[0] : b2[2];
        c0 = keep + __shfl_xor(send, 32);
    }
    {
        float keep = g2 ? b2[3] : b2[1];
        float send = g2 ? b2[1] : b2[3];
        c1 = keep + __shfl_xor(send, 32);
    }

    float y0 = fast_tanh(c0), y1 = fast_tanh(c1);
    int dimo = 16 * q + 2 * g;
    *reinterpret_cast<float2*>(fout + (size_t)node * OUT_STRIDE + dimo)
        = make_float2(y0, y1);
    if (L == 0) {
        h2 pr; pr.x = (_Float16)y0; pr.y = (_Float16)y1;
        *reinterpret_cast<h2*>(fs_out + (size_t)node * DIM + dimo) = pr;
    }
}

// ---------------------------------------------------------------------------
extern "C" void kernel_launch(void* const* d_in, const int* in_sizes, int n_in,
                              void* d_out, int out_size, void* d_ws, size_t ws_size,
                              hipStream_t stream)
{
    const float* features = (const float*)d_in[0];
    const float* rel_emb  = (const float*)d_in[1];
    const int*   adj      = (const int*)d_in[2];   // [2, E]: src | dst
    const int*   r_index  = (const int*)d_in[3];   // [2, E]: arange | rel
    const float* r_val    = (const float*)d_in[4];
    const float* attn_k   = (const float*)d_in[8]; // [DEPTH, D]
    float* out = (float*)d_out;

    const int* src   = adj;
    const int* dst   = adj + N_EDGES;
    const int* relid = r_index + N_EDGES;

    // Workspace carve-up (~39 MB)
    char* base = (char*)d_ws;
    _Float16* rhat    = (_Float16*)base;                // (R+1)*128*2 = 256256 B
    float*    att_rel = (float*)(base + 256256);        // 2*(R+1)*4   =   8008 B
    int*      rp      = (int*)(base + 264264);          // 50001*4     = 200004 B
    uint4*    einfo4  = (uint4*)(base + 464272);        // 800000*16   = 12.8 MB
    _Float16* fs0     = (_Float16*)(base + 464272 + (size_t)N_EDGES * 16); // 12.8 MB
    _Float16* fs1     = fs0 + (size_t)N_NODES * DIM;                       // 12.8 MB

    prep_rel_kernel<<<N_REL + 1, 64, 0, stream>>>(rel_emb, attn_k, rhat, att_rel);
    rowptr_kernel<<<(N_NODES + 1 + 255) / 256, 256, 0, stream>>>(src, rp);
    weights_tanh_kernel<<<(N_NODES + 3) / 4, 256, 0, stream>>>(
        features, out, fs0, dst, relid, r_val, rp, att_rel, einfo4);

    layer_fused_kernel<0><<<(N_NODES + 3) / 4, 256, 0, stream>>>(
        fs0, out + 1 * DIM, fs1, einfo4, rp, rhat);
    layer_fused_kernel<1><<<(N_NODES + 3) / 4, 256, 0, stream>>>(
        fs1, out + 2 * DIM, fs0, einfo4, rp, rhat);
}

// Round 9
// 131.433 us; speedup vs baseline: 1.1416x; 1.0233x over previous
//
#include <hip/hip_runtime.h>
#include <hip/hip_bf16.h>
#include <math.h>

// Problem constants (fixed by setup_inputs)
#define N_NODES   50000
#define N_EDGES   800000
#define N_REL     1000
#define DIM       128
#define DEPTH_L   2
#define OUT_STRIDE (DIM * (DEPTH_L + 1))   // 384

typedef _Float16 h2 __attribute__((ext_vector_type(2)));

#if defined(__has_builtin)
#if __has_builtin(__builtin_amdgcn_fdot2)
#define FDOT2(a, b, c) __builtin_amdgcn_fdot2((a), (b), (c), false)
#endif
#endif
#ifndef FDOT2
#define FDOT2(a, b, c) ((c) + (float)(a).x * (float)(b).x + (float)(a).y * (float)(b).y)
#endif

// fast tanh: (e^{2x}-1)/(e^{2x}+1), clamped so exp never overflows.
__device__ __forceinline__ float fast_tanh(float x) {
    float cx = fminf(fmaxf(x, -15.f), 15.f);
    float e = __expf(2.f * cx);
    return (e - 1.f) * __frcp_rn(e + 1.f);
}

// ---------------------------------------------------------------------------
// Kernel 1: per-relation precompute (R+1 blocks; block N_REL writes the
// zero row used by edges with r_val==0).
// ---------------------------------------------------------------------------
__global__ __launch_bounds__(64) void prep_rel_kernel(
    const float* __restrict__ rel_emb,
    const float* __restrict__ attn_k,
    _Float16* __restrict__ rhat,
    float* __restrict__ att_rel)
{
    int r = blockIdx.x;
    int lane = threadIdx.x;
    if (r == N_REL) {                       // zero row / zero logit slot
        rhat[(size_t)r * DIM + lane]      = (_Float16)0.f;
        rhat[(size_t)r * DIM + lane + 64] = (_Float16)0.f;
        if (lane < DEPTH_L) att_rel[lane * (N_REL + 1) + N_REL] = 0.f;
        return;
    }
    float v0 = rel_emb[r * DIM + lane];
    float v1 = rel_emb[r * DIM + lane + 64];
    float ss = v0 * v0 + v1 * v1;
    #pragma unroll
    for (int o = 32; o >= 1; o >>= 1) ss += __shfl_xor(ss, o);
    float inv = 1.0f / fmaxf(sqrtf(ss), 1e-12f);
    float t0 = v0 * inv, t1 = v1 * inv;
    rhat[(size_t)r * DIM + lane]      = (_Float16)t0;
    rhat[(size_t)r * DIM + lane + 64] = (_Float16)t1;
    #pragma unroll
    for (int l = 0; l < DEPTH_L; ++l) {
        float d = t0 * attn_k[l * DIM + lane] + t1 * attn_k[l * DIM + lane + 64];
        #pragma unroll
        for (int o = 32; o >= 1; o >>= 1) d += __shfl_xor(d, o);
        if (lane == 0) att_rel[l * (N_REL + 1) + r] = d;
    }
}

// ---------------------------------------------------------------------------
// Kernel 2: CSR row pointers from the sorted src array (binary search).
// ---------------------------------------------------------------------------
__global__ __launch_bounds__(256) void rowptr_kernel(
    const int* __restrict__ src, int* __restrict__ rp)
{
    int n = blockIdx.x * blockDim.x + threadIdx.x;
    if (n > N_NODES) return;
    int lo = 0, hi = N_EDGES;
    while (lo < hi) {
        int mid = (lo + hi) >> 1;
        if (src[mid] < n) lo = mid + 1; else hi = mid;
    }
    rp[n] = lo;
}

// ---------------------------------------------------------------------------
// Kernel 3: FUSED tanh0 + softmax weights for both layers + edge records.
// One wave per node; 2 waves per block (small blocks -> better residency).
// ---------------------------------------------------------------------------
__global__ __launch_bounds__(128) void weights_tanh_kernel(
    const float* __restrict__ feat, float* __restrict__ out,
    _Float16* __restrict__ fs0,
    const int* __restrict__ dst, const int* __restrict__ relid,
    const float* __restrict__ rval, const int* __restrict__ rp,
    const float* __restrict__ att_rel,
    uint4* __restrict__ einfo4)
{
    int wid  = threadIdx.x >> 6;
    int lane = threadIdx.x & 63;
    int node = blockIdx.x * 2 + wid;
    if (node >= N_NODES) return;

    // --- tanh of this node's feature row (lane: dims 2*lane, 2*lane+1) ---
    float2 v = *reinterpret_cast<const float2*>(feat + (size_t)node * DIM + 2 * lane);
    float y0 = fast_tanh(v.x), y1 = fast_tanh(v.y);
    *reinterpret_cast<float2*>(out + (size_t)node * OUT_STRIDE + 2 * lane)
        = make_float2(y0, y1);
    h2 pr; pr.x = (_Float16)y0; pr.y = (_Float16)y1;
    *reinterpret_cast<h2*>(fs0 + (size_t)node * DIM + 2 * lane) = pr;

    // --- softmax weights over this node's edges ---
    int start = rp[node], end = rp[node + 1];
    if (start >= end) return;
    const float* ar0 = att_rel;
    const float* ar1 = att_rel + (N_REL + 1);

    float m0 = -INFINITY, s0 = 0.f, m1 = -INFINITY, s1 = 0.f;
    for (int e = start + lane; e < end; e += 64) {
        int r = (rval[e] == 0.f) ? N_REL : relid[e];
        float l0 = ar0[r], l1 = ar1[r];
        if (l0 > m0) { s0 = s0 * __expf(m0 - l0) + 1.f; m0 = l0; }
        else         { s0 += __expf(l0 - m0); }
        if (l1 > m1) { s1 = s1 * __expf(m1 - l1) + 1.f; m1 = l1; }
        else         { s1 += __expf(l1 - m1); }
    }
    #pragma unroll
    for (int o = 32; o >= 1; o >>= 1) {
        float ma = __shfl_xor(m0, o), sa = __shfl_xor(s0, o);
        float mn = fmaxf(m0, ma);
        s0 = (mn == -INFINITY) ? 0.f : s0 * __expf(m0 - mn) + sa * __expf(ma - mn);
        m0 = mn;
        float mb = __shfl_xor(m1, o), sb = __shfl_xor(s1, o);
        float mo = fmaxf(m1, mb);
        s1 = (mo == -INFINITY) ? 0.f : s1 * __expf(m1 - mo) + sb * __expf(mb - mo);
        m1 = mo;
    }
    float i0 = 1.0f / s0, i1 = 1.0f / s1;
    for (int e = start + lane; e < end; e += 64) {
        int r = (rval[e] == 0.f) ? N_REL : relid[e];
        float w0 = __expf(ar0[r] - m0) * i0;
        float w1 = __expf(ar1[r] - m1) * i1;
        einfo4[e] = make_uint4((unsigned)dst[e], (unsigned)r,
                               __float_as_uint(w0), __float_as_uint(w1));
    }
}

// ---------------------------------------------------------------------------
// Kernel 4 (per layer L): FUSED gather + reflect + accumulate, f16 inputs.
// One wave per node; 2 waves per block. 16-edge iterations = two 8-edge
// sub-chunks with all loads issued before either compute. 8 lanes/edge;
// lane owns 16 dims; 3-step halving butterfly epilogue.
// ---------------------------------------------------------------------------
template<int L>
__global__ __launch_bounds__(128) void layer_fused_kernel(
    const _Float16* __restrict__ fs_in,   // [N,128] f16
    float* __restrict__ fout,             // column block in d_out
    _Float16* __restrict__ fs_out,        // [N,128] f16 mirror (L==0 only)
    const uint4* __restrict__ einfo4,
    const int* __restrict__ rp,
    const _Float16* __restrict__ rhat)    // [(R+1),128] f16
{
    int wid  = threadIdx.x >> 6;
    int lane = threadIdx.x & 63;
    int node = blockIdx.x * 2 + wid;
    if (node >= N_NODES) return;
    int start = rp[node], end = rp[node + 1];
    int g = lane >> 3;      // edge slot within sub-chunk (0..7)
    int q = lane & 7;       // dim group: dims [16q, 16q+16)

    const char* fbase = (const char*)fs_in + 32 * q;   // +16 dims * 2B per q
    const char* tbase = (const char*)rhat  + 32 * q;
    int g0 = (lane >> 3) & 1, g1 = (lane >> 4) & 1, g2 = (lane >> 5) & 1;

    float a[16];
    #pragma unroll
    for (int i = 0; i < 16; ++i) a[i] = 0.f;

    for (int e0 = start; e0 < end; e0 += 16) {
        // ---------- load phase: sub-chunk A ----------
        int eA = e0 + g;
        bool vA = (eA < end);
        int ecA = vA ? eA : (end - 1);
        uint4 eiA = einfo4[ecA];
        const uint4* hpA = reinterpret_cast<const uint4*>(fbase + (size_t)eiA.x * 256);
        const uint4* tpA = reinterpret_cast<const uint4*>(tbase + (size_t)eiA.y * 256);
        uint4 huA0 = hpA[0], huA1 = hpA[1];
        uint4 tuA0 = tpA[0], tuA1 = tpA[1];
        float wA = vA ? __uint_as_float((L == 0) ? eiA.z : eiA.w) : 0.f;

        // ---------- load phase: sub-chunk B (if present) ----------
        bool haveB = (e0 + 8 < end);
        uint4 huB0, huB1, tuB0, tuB1;
        float wB = 0.f;
        if (haveB) {
            int eB = e0 + 8 + g;
            bool vB = (eB < end);
            int ecB = vB ? eB : (end - 1);
            uint4 eiB = einfo4[ecB];
            const uint4* hpB = reinterpret_cast<const uint4*>(fbase + (size_t)eiB.x * 256);
            const uint4* tpB = reinterpret_cast<const uint4*>(tbase + (size_t)eiB.y * 256);
            huB0 = hpB[0]; huB1 = hpB[1];
            tuB0 = tpB[0]; tuB1 = tpB[1];
            wB = vB ? __uint_as_float((L == 0) ? eiB.z : eiB.w) : 0.f;
        }

        // ---------- compute A ----------
        {
            h2 hh[8], tt[8];
            hh[0] = __builtin_bit_cast(h2, huA0.x); hh[1] = __builtin_bit_cast(h2, huA0.y);
            hh[2] = __builtin_bit_cast(h2, huA0.z); hh[3] = __builtin_bit_cast(h2, huA0.w);
            hh[4] = __builtin_bit_cast(h2, huA1.x); hh[5] = __builtin_bit_cast(h2, huA1.y);
            hh[6] = __builtin_bit_cast(h2, huA1.z); hh[7] = __builtin_bit_cast(h2, huA1.w);
            tt[0] = __builtin_bit_cast(h2, tuA0.x); tt[1] = __builtin_bit_cast(h2, tuA0.y);
            tt[2] = __builtin_bit_cast(h2, tuA0.z); tt[3] = __builtin_bit_cast(h2, tuA0.w);
            tt[4] = __builtin_bit_cast(h2, tuA1.x); tt[5] = __builtin_bit_cast(h2, tuA1.y);
            tt[6] = __builtin_bit_cast(h2, tuA1.z); tt[7] = __builtin_bit_cast(h2, tuA1.w);
            float d0 = 0.f, d1 = 0.f;
            #pragma unroll
            for (int p = 0; p < 8; p += 2) {
                d0 = FDOT2(hh[p],     tt[p],     d0);
                d1 = FDOT2(hh[p + 1], tt[p + 1], d1);
            }
            float d = d0 + d1;
            d += __shfl_xor(d, 1);
            d += __shfl_xor(d, 2);
            d += __shfl_xor(d, 4);
            float cf = -2.f * wA * d;
            #pragma unroll
            for (int p = 0; p < 8; ++p) {
                a[2*p]   = fmaf(wA, (float)hh[p].x, a[2*p]);
                a[2*p]   = fmaf(cf, (float)tt[p].x, a[2*p]);
                a[2*p+1] = fmaf(wA, (float)hh[p].y, a[2*p+1]);
                a[2*p+1] = fmaf(cf, (float)tt[p].y, a[2*p+1]);
            }
        }

        // ---------- compute B ----------
        if (haveB) {
            h2 hh[8], tt[8];
            hh[0] = __builtin_bit_cast(h2, huB0.x); hh[1] = __builtin_bit_cast(h2, huB0.y);
            hh[2] = __builtin_bit_cast(h2, huB0.z); hh[3] = __builtin_bit_cast(h2, huB0.w);
            hh[4] = __builtin_bit_cast(h2, huB1.x); hh[5] = __builtin_bit_cast(h2, huB1.y);
            hh[6] = __builtin_bit_cast(h2, huB1.z); hh[7] = __builtin_bit_cast(h2, huB1.w);
            tt[0] = __builtin_bit_cast(h2, tuB0.x); tt[1] = __builtin_bit_cast(h2, tuB0.y);
            tt[2] = __builtin_bit_cast(h2, tuB0.z); tt[3] = __builtin_bit_cast(h2, tuB0.w);
            tt[4] = __builtin_bit_cast(h2, tuB1.x); tt[5] = __builtin_bit_cast(h2, tuB1.y);
            tt[6] = __builtin_bit_cast(h2, tuB1.z); tt[7] = __builtin_bit_cast(h2, tuB1.w);
            float d0 = 0.f, d1 = 0.f;
            #pragma unroll
            for (int p = 0; p < 8; p += 2) {
                d0 = FDOT2(hh[p],     tt[p],     d0);
                d1 = FDOT2(hh[p + 1], tt[p + 1], d1);
            }
            float d = d0 + d1;
            d += __shfl_xor(d, 1);
            d += __shfl_xor(d, 2);
            d += __shfl_xor(d, 4);
            float cf = -2.f * wB * d;
            #pragma unroll
            for (int p = 0; p < 8; ++p) {
                a[2*p]   = fmaf(wB, (float)hh[p].x, a[2*p]);
                a[2*p]   = fmaf(cf, (float)tt[p].x, a[2*p]);
                a[2*p+1] = fmaf(wB, (float)hh[p].y, a[2*p+1]);
                a[2*p+1] = fmaf(cf, (float)tt[p].y, a[2*p+1]);
            }
        }
    }

    // Halving butterfly over the 8 edge-groups. After 3 steps, lane (g,q)
    // holds the full sums for dims 16q+2g, 16q+2g+1.
    float b1[8];
    #pragma unroll
    for (int j = 0; j < 8; ++j) {
        int J0 = ((j >> 2) & 1) * 8 + ((j >> 1) & 1) * 4 + (j & 1);
        float keep = g0 ? a[J0 + 2] : a[J0];
        float send = g0 ? a[J0] : a[J0 + 2];
        b1[j] = keep + __shfl_xor(send, 8);
    }
    float b2[4];
    #pragma unroll
    for (int k = 0; k < 4; ++k) {
        int K0 = ((k >> 1) & 1) * 4 + (k & 1);
        float keep = g1 ? b1[K0 + 2] : b1[K0];
        float send = g1 ? b1[K0] : b1[K0 + 2];
        b2[k] = keep + __shfl_xor(send, 16);
    }
    float c0, c1;
    {
        float keep = g2 ? b2[2] : b2[0];
        float send = g2 ? b2[0] : b2[2];
        c0 = keep + __shfl_xor(send, 32);
    }
    {
        float keep = g2 ? b2[3] : b2[1];
        float send = g2 ? b2[1] : b2[3];
        c1 = keep + __shfl_xor(send, 32);
    }

    float y0 = fast_tanh(c0), y1 = fast_tanh(c1);
    int dimo = 16 * q + 2 * g;
    *reinterpret_cast<float2*>(fout + (size_t)node * OUT_STRIDE + dimo)
        = make_float2(y0, y1);
    if (L == 0) {
        h2 pr; pr.x = (_Float16)y0; pr.y = (_Float16)y1;
        *reinterpret_cast<h2*>(fs_out + (size_t)node * DIM + dimo) = pr;
    }
}

// ---------------------------------------------------------------------------
extern "C" void kernel_launch(void* const* d_in, const int* in_sizes, int n_in,
                              void* d_out, int out_size, void* d_ws, size_t ws_size,
                              hipStream_t stream)
{
    const float* features = (const float*)d_in[0];
    const float* rel_emb  = (const float*)d_in[1];
    const int*   adj      = (const int*)d_in[2];   // [2, E]: src | dst
    const int*   r_index  = (const int*)d_in[3];   // [2, E]: arange | rel
    const float* r_val    = (const float*)d_in[4];
    const float* attn_k   = (const float*)d_in[8]; // [DEPTH, D]
    float* out = (float*)d_out;

    const int* src   = adj;
    const int* dst   = adj + N_EDGES;
    const int* relid = r_index + N_EDGES;

    // Workspace carve-up (~39 MB)
    char* base = (char*)d_ws;
    _Float16* rhat    = (_Float16*)base;                // (R+1)*128*2 = 256256 B
    float*    att_rel = (float*)(base + 256256);        // 2*(R+1)*4   =   8008 B
    int*      rp      = (int*)(base + 264264);          // 50001*4     = 200004 B
    uint4*    einfo4  = (uint4*)(base + 464272);        // 800000*16   = 12.8 MB
    _Float16* fs0     = (_Float16*)(base + 464272 + (size_t)N_EDGES * 16); // 12.8 MB
    _Float16* fs1     = fs0 + (size_t)N_NODES * DIM;                       // 12.8 MB

    prep_rel_kernel<<<N_REL + 1, 64, 0, stream>>>(rel_emb, attn_k, rhat, att_rel);
    rowptr_kernel<<<(N_NODES + 1 + 255) / 256, 256, 0, stream>>>(src, rp);
    weights_tanh_kernel<<<(N_NODES + 1) / 2, 128, 0, stream>>>(
        features, out, fs0, dst, relid, r_val, rp, att_rel, einfo4);

    layer_fused_kernel<0><<<(N_NODES + 1) / 2, 128, 0, stream>>>(
        fs0, out + 1 * DIM, fs1, einfo4, rp, rhat);
    layer_fused_kernel<1><<<(N_NODES + 1) / 2, 128, 0, stream>>>(
        fs1, out + 2 * DIM, fs0, einfo4, rp, rhat);
}